// Round 5
// baseline (370.385 us; speedup 1.0000x reference)
//
#include <hip/hip_runtime.h>
#include <stdint.h>

// CIN layers: Xn[b,h,d] = sum_{j,k} W[h,j,k] * X0[b,j,d] * Xi[b,k,d] + bias[h]
// y[d,h] = sum_k Xi*W (mfma_32x32x16, A rows m=b'*16+d, B cols=32h), then
// Xacc += x0[b,j,d]*y.
// R14 post-mortem: FOUR schedules (barrier-locked, counted-vmcnt, 4-blk,
// barrier-free) all land at 105us/layer with identical pipes (Mfma 35 /
// VALU 37 / LDS ~44). Wall = SUM of pipe busy-times, invariant because the
// per-pipe WORK VOLUME is invariant. Scheduling exonerated; cut volume.
// R15: j-major stages. Pass-major visited each j twice (S=78, K=64/stage),
// executing the x0-scale (2 LDS reads + 16 unpack + 16 fma per P) TWICE per
// j. Now one stage = one j, full K=128 chain (8 MFMAs/P, af[P][0..7]
// resident, no af switch); ONE x0-scale per (j,P). S 78->39: scale-VALU,
// unpack, x0-reads, barriers, addressing all halve. MFMA/W-read/DMA volume
// unchanged. 128-thr blocks, P=2 (regs ~170 under the 256 cap of
// launch_bounds(128,2) -> no R11-style spill). LDS = 3x8KB W (3-buf,
// prefetch-2 post-barrier, counted vmcnt(4); hazard: buf[(s+2)%3] is
// neither current nor next, and its prior stage s-1 was consumed before
// barrier(s)) + 9.75KB x0 = 34.6KB -> 4 blocks/CU; grid 2048 = exactly
// 8/CU in 2 passes, no tail.

#define NB_F0 39
#define NB_H  128
#define NB_B  4096

typedef float f32x4  __attribute__((ext_vector_type(4)));
typedef float f32x16 __attribute__((ext_vector_type(16)));
typedef short s16x8  __attribute__((ext_vector_type(8)));

__device__ __forceinline__ void dma16(const void* g, void* l) {
  __builtin_amdgcn_global_load_lds(
      (const __attribute__((address_space(1))) unsigned int*)g,
      (__attribute__((address_space(3))) unsigned int*)l, 16, 0, 0);
}

__device__ __forceinline__ unsigned short rne_bf16(float f) {
  union { float f; unsigned u; } v; v.f = f;
  return (unsigned short)((v.u + 0x7fffu + ((v.u >> 16) & 1u)) >> 16);
}
__device__ __forceinline__ float bf16_to_f32(unsigned short s) {
  union { unsigned u; float f; } v; v.u = ((unsigned)s) << 16;
  return v.f;
}

// X0 f32 [B][39][16] -> X0T bf16 [B][16][64] (k=j zero-padded, layer-0 A source)
//                    -> X0c bf16 [B][39][16] with d-PERMUTED inner dim
//   (pos<->d swap bits 2,3) so a lane's 8 x0 factors for MFMA regs r=0..7
//   (d = (r&3)+8*((r>>2)&1)+4L) are one contiguous 16B run.
__global__ void prep_x0_kernel(const float* __restrict__ X0g,
                               unsigned short* __restrict__ X0T,
                               unsigned short* __restrict__ X0c) {
  const int b = blockIdx.x;
  const int t = threadIdx.x;
  {
    const int d  = t >> 4;
    const int k4 = (t & 15) << 2;
    unsigned short vv[4];
#pragma unroll
    for (int i = 0; i < 4; ++i) {
      const int k = k4 + i;
      vv[i] = (k < NB_F0) ? rne_bf16(X0g[(size_t)b * (NB_F0 * 16) + k * 16 + d])
                          : (unsigned short)0;
    }
    ushort4 pk; pk.x = vv[0]; pk.y = vv[1]; pk.z = vv[2]; pk.w = vv[3];
    *(ushort4*)&X0T[((size_t)b * 16 + d) * 64 + k4] = pk;
  }
  for (int idx = t; idx < NB_F0 * 16; idx += 256) {
    const int j = idx >> 4, pos = idx & 15;
    const int d = (pos & 3) | (((pos >> 3) & 1) << 2) | (((pos >> 2) & 1) << 3);
    X0c[(size_t)b * (NB_F0 * 16) + idx] =
        rne_bf16(X0g[(size_t)b * (NB_F0 * 16) + j * 16 + d]);
  }
}

// W f32 [128][39*Fi] -> Wf bf16 fragment-linear for 32x32x16 B-operand:
//   Wf[(((j*4 + t)*KC16 + c)*64 + lane)*8 + i]
//     = W[h = t*32 + (lane&31)][j, k = c*16 + (lane>>5)*8 + i]   (0 if k>=Fi)
__global__ void prep_w_kernel(const float* __restrict__ Wsrc,
                              unsigned short* __restrict__ Wdst,
                              int Fi, int kshift, int total) {
  int idx = blockIdx.x * 256 + threadIdx.x;
  if (idx >= total) return;
  const int i    = idx & 7;
  const int lane = (idx >> 3) & 63;
  const int c    = (idx >> 9) & ((1 << kshift) - 1);
  const int jt   = idx >> (9 + kshift);
  const int t    = jt & 3;
  const int j    = jt >> 2;
  const int h = t * 32 + (lane & 31);
  const int k = c * 16 + ((lane >> 5) << 3) + i;
  unsigned short v = 0;
  if (k < Fi) v = rne_bf16(Wsrc[(size_t)h * (NB_F0 * Fi) + j * Fi + k]);
  Wdst[idx] = v;
}

template <int FI_PAD, bool STORE_XN>
__global__ __launch_bounds__(128, 2) void cin_layer(
    const unsigned short* __restrict__ Wf,   // fragment-linear W (see prep)
    const unsigned short* __restrict__ XiT,  // [B][16][FI_PAD] bf16
    const unsigned short* __restrict__ X0c,  // [B][39][16] bf16, d-permuted
    const float* __restrict__ bias,          // [128]
    unsigned short* __restrict__ XnT,        // [B][16][128] bf16 (or unused)
    float* __restrict__ outp)                // d_out + layer*128, stride 384
{
  constexpr int KC16 = FI_PAD / 16;    // k-chunks per j (4 or 8)
  constexpr int CPW  = KC16 / 2;       // DMA chunks per wave per stage
  constexpr int S    = NB_F0;          // j-major: one stage per j

  // 3-deep W stage buffers (one j each: KC16*512 shorts = 4/8 KB)
  __shared__ __attribute__((aligned(16))) unsigned short Wlds[3][KC16 * 512];
  __shared__ __attribute__((aligned(16))) unsigned short x0s[8 * NB_F0 * 16];

  const int tid  = threadIdx.x;
  const int lane = tid & 63;
  const int wv   = tid >> 6;        // 0..1
  const int L    = lane >> 5;       // k-half selector within a chunk
  const int col  = lane & 31;       // A row m / B col
  const int ht   = blockIdx.x >> 9;            // 0..3 (32 h each)
  const int bblk = (blockIdx.x & 511) * 8;     // 8 b per block
  const int bwave = bblk + wv * 4;             // 4 b per wave

  // ---- W DMA: wave wv stages chunks c = CPW*wv .. CPW*wv+CPW-1 ----
  auto dma_stage = [&](int j, int buf) {
#pragma unroll
    for (int cc = 0; cc < CPW; ++cc) {
      const int c = CPW * wv + cc;
      const unsigned short* src =
          Wf + ((size_t)(j * 4 + ht) * KC16 + c) * 512 + lane * 8;
      dma16(src, &Wlds[buf][c * 512]);
    }
  };

  // ---- stage x0 factors (bf16 d-permuted, flat coalesced copy) ----
  {
    const unsigned short* src = X0c + (size_t)bblk * (NB_F0 * 16);
    for (int c = tid; c < (8 * NB_F0 * 16) / 8; c += 128)
      *(s16x8*)&x0s[c * 8] = *(const s16x8*)&src[c * 8];
  }

  // ---- Xi A-fragments: all KC16 k-chunks resident (no mid-loop switch) ----
  s16x8 af[2][KC16];
#pragma unroll
  for (int P = 0; P < 2; ++P) {
    const unsigned short* base = XiT +
        ((size_t)(bwave + 2 * P + (col >> 4)) * 16 + (col & 15)) * FI_PAD +
        L * 8;
#pragma unroll
    for (int c = 0; c < KC16; ++c) af[P][c] = *(const s16x8*)(base + c * 16);
  }

  f32x16 Xacc[2], kZero;
#pragma unroll
  for (int r = 0; r < 16; ++r) kZero[r] = 0.f;
#pragma unroll
  for (int P = 0; P < 2; ++P) Xacc[P] = kZero;

  // Publish x0s; full drain also retires x0/af global loads so the counted
  // vmcnt below sees only W DMAs.
  __syncthreads();

  // ---- prologue: 2 stages in flight ----
  dma_stage(0, 0);
  dma_stage(1, 1);

  const int x0base = (wv * 4) * (NB_F0 * 16) + L * 8;

  int bc = 0;          // buffer holding stage s
  for (int s = 0; s < S; ++s) {
    // In flight: stage s (CPW own chunks) + stage s+1 (CPW). vmcnt(CPW)
    // retires own stage-s chunks; barrier extends to the other wave's.
    if constexpr (CPW == 4) asm volatile("s_waitcnt vmcnt(4)" ::: "memory");
    else                    asm volatile("s_waitcnt vmcnt(2)" ::: "memory");
    __builtin_amdgcn_s_barrier();
    asm volatile("" ::: "memory");   // fence: no ds_read hoist above barrier

    // Prefetch stage s+2 into buf (bc+2)%3: neither current (bc) nor next;
    // its old contents (stage s-1) were consumed before barrier(s). Tail
    // wraps to a dummy refetch (never read) to keep the vmcnt literal exact.
    const int bp = bc == 0 ? 2 : bc - 1;   // (bc+2)%3
    const int sn = s + 2;
    dma_stage(sn < S ? sn : sn - S, bp);

    const unsigned short* wb = &Wlds[bc][lane * 8];
    s16x8 w[KC16];
#pragma unroll
    for (int c = 0; c < KC16; ++c) w[c] = *(const s16x8*)(wb + c * 512);

#pragma unroll
    for (int P = 0; P < 2; ++P) {
      // Full K=FI_PAD chain for this j: one y, ONE x0-scale.
      f32x16 y = __builtin_amdgcn_mfma_f32_32x32x16_bf16(af[P][0], w[0],
                                                         kZero, 0, 0, 0);
#pragma unroll
      for (int c = 1; c < KC16; ++c)
        y = __builtin_amdgcn_mfma_f32_32x32x16_bf16(af[P][c], w[c], y, 0, 0, 0);

      // x0 scale: regs 0-7 <- b'=2P (this lane's L 8-run), 8-15 <- b'=2P+1.
      // Unpack packed bf16 dwords to f32 pairs; elementwise_fma -> v_pk_fma_f32.
      const uint4 xu0 = *(const uint4*)
          &x0s[x0base + (2 * P + 0) * (NB_F0 * 16) + s * 16];
      const uint4 xu1 = *(const uint4*)
          &x0s[x0base + (2 * P + 1) * (NB_F0 * 16) + s * 16];
      const unsigned wd[8] = {xu0.x, xu0.y, xu0.z, xu0.w,
                              xu1.x, xu1.y, xu1.z, xu1.w};
      f32x16 xsc;
#pragma unroll
      for (int i = 0; i < 8; ++i) {
        xsc[2 * i]     = __uint_as_float(wd[i] << 16);
        xsc[2 * i + 1] = __uint_as_float(wd[i] & 0xffff0000u);
      }
      Xacc[P] = __builtin_elementwise_fma(xsc, y, Xacc[P]);
    }

    bc = bc == 2 ? 0 : bc + 1;
  }

  // ---- epilogue ----
  const float bias_v = bias[ht * 32 + col];
#pragma unroll
  for (int P = 0; P < 2; ++P) {
#pragma unroll
    for (int bh = 0; bh < 2; ++bh) {
      const int b = bwave + 2 * P + bh;
      float v[8];
#pragma unroll
      for (int m = 0; m < 8; ++m) v[m] = Xacc[P][bh * 8 + m] + bias_v;
      if (STORE_XN) {
#pragma unroll
        for (int m = 0; m < 8; ++m) {
          const int d = (m & 3) + 8 * ((m >> 2) & 1) + 4 * L;
          XnT[((size_t)b * 16 + d) * NB_H + ht * 32 + col] = rne_bf16(v[m]);
        }
      }
      float tot = ((v[0] + v[1]) + (v[2] + v[3])) + ((v[4] + v[5]) + (v[6] + v[7]));
      tot += __shfl_xor(tot, 32);
      if (lane < 32) outp[(size_t)b * 384 + ht * 32 + lane] = tot;
    }
  }
}

extern "C" void kernel_launch(void* const* d_in, const int* in_sizes, int n_in,
                              void* d_out, int out_size, void* d_ws, size_t ws_size,
                              hipStream_t stream) {
  (void)in_sizes; (void)n_in; (void)out_size; (void)ws_size;
  const float* X0g = (const float*)d_in[0];
  const float* W0  = (const float*)d_in[1];
  const float* b0  = (const float*)d_in[2];
  const float* W1  = (const float*)d_in[3];
  const float* b1  = (const float*)d_in[4];
  const float* W2  = (const float*)d_in[5];
  const float* b2  = (const float*)d_in[6];
  float* out = (float*)d_out;

  char* p = (char*)d_ws;
  unsigned short* X0T = (unsigned short*)p; p += (size_t)NB_B * 16 * 64 * 2;
  unsigned short* X0c = (unsigned short*)p; p += (size_t)NB_B * NB_F0 * 16 * 2;
  unsigned short* X1T = (unsigned short*)p; p += (size_t)NB_B * 16 * 128 * 2;
  unsigned short* X2T = (unsigned short*)p; p += (size_t)NB_B * 16 * 128 * 2;
  unsigned short* Wf0 = (unsigned short*)p; p += (size_t)NB_F0 * 4 * 4 * 512 * 2;
  unsigned short* Wf1 = (unsigned short*)p; p += (size_t)NB_F0 * 4 * 8 * 512 * 2;
  unsigned short* Wf2 = (unsigned short*)p; p += (size_t)NB_F0 * 4 * 8 * 512 * 2;

  hipLaunchKernelGGL(prep_x0_kernel, dim3(NB_B), dim3(256), 0, stream,
                     X0g, X0T, X0c);
  const int tw0  = NB_F0 * 4 * 4 * 512;   // KC16=4
  const int tw12 = NB_F0 * 4 * 8 * 512;   // KC16=8
  hipLaunchKernelGGL(prep_w_kernel, dim3((tw0 + 255) / 256), dim3(256), 0, stream,
                     W0, Wf0, 39, 2, tw0);
  hipLaunchKernelGGL(prep_w_kernel, dim3((tw12 + 255) / 256), dim3(256), 0, stream,
                     W1, Wf1, 128, 3, tw12);
  hipLaunchKernelGGL(prep_w_kernel, dim3((tw12 + 255) / 256), dim3(256), 0, stream,
                     W2, Wf2, 128, 3, tw12);

  hipLaunchKernelGGL((cin_layer<64, true>),   dim3(2048), dim3(128), 0, stream,
                     Wf0, X0T, X0c, b0, X1T, out + 0);
  hipLaunchKernelGGL((cin_layer<128, true>),  dim3(2048), dim3(128), 0, stream,
                     Wf1, X1T, X0c, b1, X2T, out + 128);
  hipLaunchKernelGGL((cin_layer<128, false>), dim3(2048), dim3(128), 0, stream,
                     Wf2, X2T, X0c, b2, (unsigned short*)nullptr, out + 256);
}

// Round 6
// 314.208 us; speedup vs baseline: 1.1788x; 1.1788x over previous
//
#include <hip/hip_runtime.h>
#include <stdint.h>

// CIN layers: Xn[b,h,d] = sum_{j,k} W[h,j,k] * X0[b,j,d] * Xi[b,k,d] + bias[h]
// y[d,h] = sum_k Xi*W (mfma_32x32x16, A rows m=b'*16+d, B cols=32h), then
// Xacc += x0[b,j,d]*y.
// R15 post-mortem: j-major halved VALU as predicted (VALUBusy 37->20.7%) but
// W-LDS reads doubled per-b (8 b128/stage for 4 b) -> LDS pipe ~37us/CU and
// dur 124us. Wall = MFMA(36) + LDS(37) + VALU(26). MFMA is at its 33us floor;
// W-through-LDS is the waste: every wave re-reads the stage from LDS, plus
// DMA+barrier overhead. W is L2-resident and the VMEM pipe is idle (HBM 4%).
// R16: keep j-major (VALU win), move W to global->register ping-pong.
// No W LDS, no global_load_lds, ZERO barriers in the main loop (only the x0
// publish). LDS carries only x0 (19.5KB) -> LDS pipe ~12us/CU. R11's spill
// trap avoided: j-major P=2 state = af 64 + wA/wB 64 + Xacc 32(acc) + addr
// ~160 unified < 256 cap at launch_bounds(128,2) -> 3 waves/SIMD. Compiler
// auto-vmcnts the register loads; prefetch distance = 1 stage (~300cy MFMA+
// scale) covers ~200cy L2 latency. Static wA/wB unroll-by-2 (rule #20: no
// runtime-indexed reg arrays). Grid 2048 = 512 bgrp x 4 ht; 12 independent
// waves/CU, phase-decorrelated.

#define NB_F0 39
#define NB_H  128
#define NB_B  4096

typedef float f32x4  __attribute__((ext_vector_type(4)));
typedef float f32x16 __attribute__((ext_vector_type(16)));
typedef short s16x8  __attribute__((ext_vector_type(8)));

__device__ __forceinline__ unsigned short rne_bf16(float f) {
  union { float f; unsigned u; } v; v.f = f;
  return (unsigned short)((v.u + 0x7fffu + ((v.u >> 16) & 1u)) >> 16);
}
__device__ __forceinline__ float bf16_to_f32(unsigned short s) {
  union { unsigned u; float f; } v; v.u = ((unsigned)s) << 16;
  return v.f;
}

// X0 f32 [B][39][16] -> X0T bf16 [B][16][64] (k=j zero-padded, layer-0 A source)
//                    -> X0c bf16 [B][39][16] with d-PERMUTED inner dim
//   (pos<->d swap bits 2,3) so a lane's 8 x0 factors for MFMA regs r=0..7
//   (d = (r&3)+8*((r>>2)&1)+4L) are one contiguous 16B run.
__global__ void prep_x0_kernel(const float* __restrict__ X0g,
                               unsigned short* __restrict__ X0T,
                               unsigned short* __restrict__ X0c) {
  const int b = blockIdx.x;
  const int t = threadIdx.x;
  {
    const int d  = t >> 4;
    const int k4 = (t & 15) << 2;
    unsigned short vv[4];
#pragma unroll
    for (int i = 0; i < 4; ++i) {
      const int k = k4 + i;
      vv[i] = (k < NB_F0) ? rne_bf16(X0g[(size_t)b * (NB_F0 * 16) + k * 16 + d])
                          : (unsigned short)0;
    }
    ushort4 pk; pk.x = vv[0]; pk.y = vv[1]; pk.z = vv[2]; pk.w = vv[3];
    *(ushort4*)&X0T[((size_t)b * 16 + d) * 64 + k4] = pk;
  }
  for (int idx = t; idx < NB_F0 * 16; idx += 256) {
    const int j = idx >> 4, pos = idx & 15;
    const int d = (pos & 3) | (((pos >> 3) & 1) << 2) | (((pos >> 2) & 1) << 3);
    X0c[(size_t)b * (NB_F0 * 16) + idx] =
        rne_bf16(X0g[(size_t)b * (NB_F0 * 16) + j * 16 + d]);
  }
}

// W f32 [128][39*Fi] -> Wf bf16 fragment-linear for 32x32x16 B-operand:
//   Wf[(((j*4 + t)*KC16 + c)*64 + lane)*8 + i]
//     = W[h = t*32 + (lane&31)][j, k = c*16 + (lane>>5)*8 + i]   (0 if k>=Fi)
__global__ void prep_w_kernel(const float* __restrict__ Wsrc,
                              unsigned short* __restrict__ Wdst,
                              int Fi, int kshift, int total) {
  int idx = blockIdx.x * 256 + threadIdx.x;
  if (idx >= total) return;
  const int i    = idx & 7;
  const int lane = (idx >> 3) & 63;
  const int c    = (idx >> 9) & ((1 << kshift) - 1);
  const int jt   = idx >> (9 + kshift);
  const int t    = jt & 3;
  const int j    = jt >> 2;
  const int h = t * 32 + (lane & 31);
  const int k = c * 16 + ((lane >> 5) << 3) + i;
  unsigned short v = 0;
  if (k < Fi) v = rne_bf16(Wsrc[(size_t)h * (NB_F0 * Fi) + j * Fi + k]);
  Wdst[idx] = v;
}

template <int FI_PAD, bool STORE_XN>
__global__ __launch_bounds__(128, 2) void cin_layer(
    const unsigned short* __restrict__ Wf,   // fragment-linear W (see prep)
    const unsigned short* __restrict__ XiT,  // [B][16][FI_PAD] bf16
    const unsigned short* __restrict__ X0c,  // [B][39][16] bf16, d-permuted
    const float* __restrict__ bias,          // [128]
    unsigned short* __restrict__ XnT,        // [B][16][128] bf16 (or unused)
    float* __restrict__ outp)                // d_out + layer*128, stride 384
{
  constexpr int KC16 = FI_PAD / 16;    // k-chunks per j (4 or 8)
  constexpr int S    = NB_F0;          // j-major: one stage per j

  __shared__ __attribute__((aligned(16))) unsigned short x0s[8 * NB_F0 * 16];

  const int tid  = threadIdx.x;
  const int lane = tid & 63;
  const int wv   = tid >> 6;        // 0..1
  const int L    = lane >> 5;       // k-half selector within a chunk
  const int col  = lane & 31;       // A row m / B col
  const int ht   = blockIdx.x >> 9;            // 0..3 (32 h each)
  const int bblk = (blockIdx.x & 511) * 8;     // 8 b per block
  const int bwave = bblk + wv * 4;             // 4 b per wave

  // ---- stage x0 factors (bf16 d-permuted, flat coalesced copy) ----
  {
    const unsigned short* src = X0c + (size_t)bblk * (NB_F0 * 16);
    for (int c = tid; c < (8 * NB_F0 * 16) / 8; c += 128)
      *(s16x8*)&x0s[c * 8] = *(const s16x8*)&src[c * 8];
  }

  // ---- Xi A-fragments: all KC16 k-chunks resident (no mid-loop switch) ----
  s16x8 af[2][KC16];
#pragma unroll
  for (int P = 0; P < 2; ++P) {
    const unsigned short* base = XiT +
        ((size_t)(bwave + 2 * P + (col >> 4)) * 16 + (col & 15)) * FI_PAD +
        L * 8;
#pragma unroll
    for (int c = 0; c < KC16; ++c) af[P][c] = *(const s16x8*)(base + c * 16);
  }

  f32x16 Xacc[2], kZero;
#pragma unroll
  for (int r = 0; r < 16; ++r) kZero[r] = 0.f;
#pragma unroll
  for (int P = 0; P < 2; ++P) Xacc[P] = kZero;

  __syncthreads();   // publish x0s; the ONLY barrier in this kernel

  // ---- W fragments straight from global (L2-hot) into registers ----
  const s16x8* __restrict__ Wf8 = (const s16x8*)Wf;
  auto wload = [&](int j, s16x8 (&w)[KC16]) {
    const s16x8* p = Wf8 + ((size_t)(j * 4 + ht) * KC16) * 64 + lane;
#pragma unroll
    for (int c = 0; c < KC16; ++c) w[c] = p[c * 64];
  };

  const int x0base = (wv * 4) * (NB_F0 * 16) + L * 8;

  auto compute = [&](int s, const s16x8 (&w)[KC16]) {
#pragma unroll
    for (int P = 0; P < 2; ++P) {
      // Full K=FI_PAD chain for this j: one y, ONE x0-scale.
      f32x16 y = __builtin_amdgcn_mfma_f32_32x32x16_bf16(af[P][0], w[0],
                                                         kZero, 0, 0, 0);
#pragma unroll
      for (int c = 1; c < KC16; ++c)
        y = __builtin_amdgcn_mfma_f32_32x32x16_bf16(af[P][c], w[c], y, 0, 0, 0);

      // x0 scale: regs 0-7 <- b'=2P (this lane's L 8-run), 8-15 <- b'=2P+1.
      // Unpack packed bf16 dwords to f32 pairs; elementwise_fma -> v_pk_fma_f32.
      const uint4 xu0 = *(const uint4*)
          &x0s[x0base + (2 * P + 0) * (NB_F0 * 16) + s * 16];
      const uint4 xu1 = *(const uint4*)
          &x0s[x0base + (2 * P + 1) * (NB_F0 * 16) + s * 16];
      const unsigned wd[8] = {xu0.x, xu0.y, xu0.z, xu0.w,
                              xu1.x, xu1.y, xu1.z, xu1.w};
      f32x16 xsc;
#pragma unroll
      for (int i = 0; i < 8; ++i) {
        xsc[2 * i]     = __uint_as_float(wd[i] << 16);
        xsc[2 * i + 1] = __uint_as_float(wd[i] & 0xffff0000u);
      }
      Xacc[P] = __builtin_elementwise_fma(xsc, y, Xacc[P]);
    }
  };

  // ---- barrier-free main loop: W reg ping-pong, prefetch 1 stage ahead ----
  s16x8 wA[KC16], wB[KC16];
  wload(0, wA);
  wload(1, wB);
  int s = 0;
  for (; s + 2 <= S; s += 2) {
    compute(s, wA);            // compiler inserts counted vmcnt before use
    wload(s + 2 < S ? s + 2 : 0, wA);   // reissue after consumption (WAR ok)
    compute(s + 1, wB);
    if (s + 3 < S) wload(s + 3, wB);
  }
  if (s < S) compute(s, wA);   // odd-S tail (S=39)

  // ---- epilogue ----
  const float bias_v = bias[ht * 32 + col];
#pragma unroll
  for (int P = 0; P < 2; ++P) {
#pragma unroll
    for (int bh = 0; bh < 2; ++bh) {
      const int b = bwave + 2 * P + bh;
      float v[8];
#pragma unroll
      for (int m = 0; m < 8; ++m) v[m] = Xacc[P][bh * 8 + m] + bias_v;
      if (STORE_XN) {
#pragma unroll
        for (int m = 0; m < 8; ++m) {
          const int d = (m & 3) + 8 * ((m >> 2) & 1) + 4 * L;
          XnT[((size_t)b * 16 + d) * NB_H + ht * 32 + col] = rne_bf16(v[m]);
        }
      }
      float tot = ((v[0] + v[1]) + (v[2] + v[3])) + ((v[4] + v[5]) + (v[6] + v[7]));
      tot += __shfl_xor(tot, 32);
      if (lane < 32) outp[(size_t)b * 384 + ht * 32 + lane] = tot;
    }
  }
}

extern "C" void kernel_launch(void* const* d_in, const int* in_sizes, int n_in,
                              void* d_out, int out_size, void* d_ws, size_t ws_size,
                              hipStream_t stream) {
  (void)in_sizes; (void)n_in; (void)out_size; (void)ws_size;
  const float* X0g = (const float*)d_in[0];
  const float* W0  = (const float*)d_in[1];
  const float* b0  = (const float*)d_in[2];
  const float* W1  = (const float*)d_in[3];
  const float* b1  = (const float*)d_in[4];
  const float* W2  = (const float*)d_in[5];
  const float* b2  = (const float*)d_in[6];
  float* out = (float*)d_out;

  char* p = (char*)d_ws;
  unsigned short* X0T = (unsigned short*)p; p += (size_t)NB_B * 16 * 64 * 2;
  unsigned short* X0c = (unsigned short*)p; p += (size_t)NB_B * NB_F0 * 16 * 2;
  unsigned short* X1T = (unsigned short*)p; p += (size_t)NB_B * 16 * 128 * 2;
  unsigned short* X2T = (unsigned short*)p; p += (size_t)NB_B * 16 * 128 * 2;
  unsigned short* Wf0 = (unsigned short*)p; p += (size_t)NB_F0 * 4 * 4 * 512 * 2;
  unsigned short* Wf1 = (unsigned short*)p; p += (size_t)NB_F0 * 4 * 8 * 512 * 2;
  unsigned short* Wf2 = (unsigned short*)p; p += (size_t)NB_F0 * 4 * 8 * 512 * 2;

  hipLaunchKernelGGL(prep_x0_kernel, dim3(NB_B), dim3(256), 0, stream,
                     X0g, X0T, X0c);
  const int tw0  = NB_F0 * 4 * 4 * 512;   // KC16=4
  const int tw12 = NB_F0 * 4 * 8 * 512;   // KC16=8
  hipLaunchKernelGGL(prep_w_kernel, dim3((tw0 + 255) / 256), dim3(256), 0, stream,
                     W0, Wf0, 39, 2, tw0);
  hipLaunchKernelGGL(prep_w_kernel, dim3((tw12 + 255) / 256), dim3(256), 0, stream,
                     W1, Wf1, 128, 3, tw12);
  hipLaunchKernelGGL(prep_w_kernel, dim3((tw12 + 255) / 256), dim3(256), 0, stream,
                     W2, Wf2, 128, 3, tw12);

  hipLaunchKernelGGL((cin_layer<64, true>),   dim3(2048), dim3(128), 0, stream,
                     Wf0, X0T, X0c, b0, X1T, out + 0);
  hipLaunchKernelGGL((cin_layer<128, true>),  dim3(2048), dim3(128), 0, stream,
                     Wf1, X1T, X0c, b1, X2T, out + 128);
  hipLaunchKernelGGL((cin_layer<128, false>), dim3(2048), dim3(128), 0, stream,
                     Wf2, X2T, X0c, b2, (unsigned short*)nullptr, out + 256);
}

// Round 7
// 308.133 us; speedup vs baseline: 1.2020x; 1.0197x over previous
//
#include <hip/hip_runtime.h>
#include <stdint.h>

// CIN layers: Xn[b,h,d] = sum_{j,k} W[h,j,k] * X0[b,j,d] * Xi[b,k,d] + bias[h]
// y[d,h] = sum_k Xi*W (mfma_32x32x16, A rows m=b'*16+d, B cols=32h), then
// Xacc += x0[b,j,d]*y.
// R16 post-mortem: six structures all land 104-124us/layer, MfmaUtil pinned
// 31-36% (~805 TF = the m97-class plateau). Scheduling grafts exhausted; the
// remaining wins are pure work-volume arithmetic OUTSIDE the loop: L0 (~52us)
// + preps/gaps (~35us) + the X1T/X2T global round-trip (67 MB of the 78 MB
// HBM traffic: 64 scattered 2B stores/wave, re-fetched cross-XCD as the next
// layer's A-fragments).
// R17: FUSE all 3 layers in one kernel; Xn handed over via LDS. Block =
// 256 thr = 4 waves; wave wv owns h-tile wv (block covers all 128 h) x 4 b
// (P=2 chains, the register-lean config). L0: af from X0T global; epilogue
// writes X1 to LDS[4b][16d][128k] (the exact A-fragment layout, scalar u16,
// 2-way-conflict max); barrier; L1 af from LDS -> X2 LDS; barrier; L2 -> sums
// only. Inner loop = R16 verbatim (j-major, W global->reg ping-pong, zero
// in-loop barriers). launch_bounds(256,1) -> VGPR cap 256 (empirical: cap =
// 256/min_arg; the (128,2)->128 cap caused R16's one-time spill).
// Kills: 2 launches+gaps, 33.6MB stores + 33.6MB re-reads, XnT workspaces.
// Grid 1024 = 4096/4 b-groups; LDS 4992(x0) + 2x16KB(X) = 37.8KB.

#define NB_F0 39
#define NB_H  128
#define NB_B  4096

typedef float f32x16 __attribute__((ext_vector_type(16)));
typedef short s16x8  __attribute__((ext_vector_type(8)));

template <int N> struct IC { static constexpr int value = N; };

__device__ __forceinline__ unsigned short rne_bf16(float f) {
  union { float f; unsigned u; } v; v.f = f;
  return (unsigned short)((v.u + 0x7fffu + ((v.u >> 16) & 1u)) >> 16);
}

// X0 f32 [B][39][16] -> X0T bf16 [B][16][64] (k=j zero-padded, layer-0 A source)
//                    -> X0c bf16 [B][39][16] with d-PERMUTED inner dim
//   (pos<->d swap bits 2,3) so a lane's 8 x0 factors for MFMA regs r=0..7
//   (d = (r&3)+8*((r>>2)&1)+4L) are one contiguous 16B run.
__global__ void prep_x0_kernel(const float* __restrict__ X0g,
                               unsigned short* __restrict__ X0T,
                               unsigned short* __restrict__ X0c) {
  const int b = blockIdx.x;
  const int t = threadIdx.x;
  {
    const int d  = t >> 4;
    const int k4 = (t & 15) << 2;
    unsigned short vv[4];
#pragma unroll
    for (int i = 0; i < 4; ++i) {
      const int k = k4 + i;
      vv[i] = (k < NB_F0) ? rne_bf16(X0g[(size_t)b * (NB_F0 * 16) + k * 16 + d])
                          : (unsigned short)0;
    }
    ushort4 pk; pk.x = vv[0]; pk.y = vv[1]; pk.z = vv[2]; pk.w = vv[3];
    *(ushort4*)&X0T[((size_t)b * 16 + d) * 64 + k4] = pk;
  }
  for (int idx = t; idx < NB_F0 * 16; idx += 256) {
    const int j = idx >> 4, pos = idx & 15;
    const int d = (pos & 3) | (((pos >> 3) & 1) << 2) | (((pos >> 2) & 1) << 3);
    X0c[(size_t)b * (NB_F0 * 16) + idx] =
        rne_bf16(X0g[(size_t)b * (NB_F0 * 16) + j * 16 + d]);
  }
}

// W f32 [128][39*Fi] -> Wf bf16 fragment-linear for 32x32x16 B-operand:
//   Wf[(((j*4 + t)*KC16 + c)*64 + lane)*8 + i]
//     = W[h = t*32 + (lane&31)][j, k = c*16 + (lane>>5)*8 + i]   (0 if k>=Fi)
__global__ void prep_w_kernel(const float* __restrict__ Wsrc,
                              unsigned short* __restrict__ Wdst,
                              int Fi, int kshift, int total) {
  int idx = blockIdx.x * 256 + threadIdx.x;
  if (idx >= total) return;
  const int i    = idx & 7;
  const int lane = (idx >> 3) & 63;
  const int c    = (idx >> 9) & ((1 << kshift) - 1);
  const int jt   = idx >> (9 + kshift);
  const int t    = jt & 3;
  const int j    = jt >> 2;
  const int h = t * 32 + (lane & 31);
  const int k = c * 16 + ((lane >> 5) << 3) + i;
  unsigned short v = 0;
  if (k < Fi) v = rne_bf16(Wsrc[(size_t)h * (NB_F0 * Fi) + j * Fi + k]);
  Wdst[idx] = v;
}

__global__ __launch_bounds__(256, 1) void cin_fused(
    const unsigned short* __restrict__ Wf0,
    const unsigned short* __restrict__ Wf1,
    const unsigned short* __restrict__ Wf2,
    const unsigned short* __restrict__ X0T,  // [B][16][64] bf16 (k zero-pad)
    const unsigned short* __restrict__ X0c,  // [B][39][16] bf16, d-permuted
    const float* __restrict__ bias0,
    const float* __restrict__ bias1,
    const float* __restrict__ bias2,
    float* __restrict__ outp)                // [B][384]
{
  __shared__ __attribute__((aligned(16))) unsigned short x0s[4 * NB_F0 * 16];
  __shared__ __attribute__((aligned(16))) unsigned short Xa[4 * 16 * 128];
  __shared__ __attribute__((aligned(16))) unsigned short Xb[4 * 16 * 128];

  const int tid  = threadIdx.x;
  const int lane = tid & 63;
  const int wv   = tid >> 6;        // h-tile: h = wv*32 + col
  const int L    = lane >> 5;       // k-half selector within a 16-chunk
  const int col  = lane & 31;       // A row m / B col
  const int bblk = blockIdx.x * 4;  // 4 b per block

  // ---- stage x0 factors (bf16 d-permuted, flat coalesced copy) ----
  {
    const unsigned short* src = X0c + (size_t)bblk * (NB_F0 * 16);
    for (int c = tid; c < (4 * NB_F0 * 16) / 8; c += 256)
      *(s16x8*)&x0s[c * 8] = *(const s16x8*)&src[c * 8];
  }
  __syncthreads();   // publish x0s

  const int x0base = L * 8;   // all waves share the block's 4 b (broadcast)

  // One CIN layer. KC16 = K-chunks (4 for Fi=64-pad, 8 for Fi=128).
  // af_base: Xi source in A-fragment layout [b][16 d][KC16*16 k] — global
  // (L0) or LDS-generic (L1/L2). xn: LDS dest for Xn (or nullptr).
  auto layer = [&](auto kc, const unsigned short* __restrict__ Wl,
                   const unsigned short* af_base, const float* __restrict__ bv,
                   float* __restrict__ op, unsigned short* xn) {
    constexpr int KC16 = decltype(kc)::value;
    constexpr int FI   = KC16 * 16;

    // ---- Xi A-fragments: chain P covers b_local = 2P + (col>>4) ----
    s16x8 af[2][KC16];
#pragma unroll
    for (int P = 0; P < 2; ++P) {
      const unsigned short* base = af_base +
          (size_t)(2 * P + (col >> 4)) * (16 * FI) + (col & 15) * FI + L * 8;
#pragma unroll
      for (int c = 0; c < KC16; ++c) af[P][c] = *(const s16x8*)(base + c * 16);
    }

    f32x16 Xacc[2], kZero;
#pragma unroll
    for (int r = 0; r < 16; ++r) kZero[r] = 0.f;
#pragma unroll
    for (int P = 0; P < 2; ++P) Xacc[P] = kZero;

    // ---- W fragments straight from global (L2-hot) into registers ----
    const s16x8* __restrict__ W8 = (const s16x8*)Wl;
    auto wload = [&](int j, s16x8 (&w)[KC16]) {
      const s16x8* p = W8 + ((size_t)(j * 4 + wv) * KC16) * 64 + lane;
#pragma unroll
      for (int c = 0; c < KC16; ++c) w[c] = p[c * 64];
    };

    auto compute = [&](int s, const s16x8 (&w)[KC16]) {
#pragma unroll
      for (int P = 0; P < 2; ++P) {
        f32x16 y = __builtin_amdgcn_mfma_f32_32x32x16_bf16(af[P][0], w[0],
                                                           kZero, 0, 0, 0);
#pragma unroll
        for (int c = 1; c < KC16; ++c)
          y = __builtin_amdgcn_mfma_f32_32x32x16_bf16(af[P][c], w[c], y,
                                                      0, 0, 0);
        // x0 scale: regs 0-7 <- b'=2P (this lane's L 8-run), 8-15 <- 2P+1.
        const uint4 xu0 = *(const uint4*)
            &x0s[x0base + (2 * P + 0) * (NB_F0 * 16) + s * 16];
        const uint4 xu1 = *(const uint4*)
            &x0s[x0base + (2 * P + 1) * (NB_F0 * 16) + s * 16];
        const unsigned wd[8] = {xu0.x, xu0.y, xu0.z, xu0.w,
                                xu1.x, xu1.y, xu1.z, xu1.w};
        f32x16 xsc;
#pragma unroll
        for (int i = 0; i < 8; ++i) {
          xsc[2 * i]     = __uint_as_float(wd[i] << 16);
          xsc[2 * i + 1] = __uint_as_float(wd[i] & 0xffff0000u);
        }
        Xacc[P] = __builtin_elementwise_fma(xsc, y, Xacc[P]);
      }
    };

    // ---- barrier-free main loop: W reg ping-pong, 1-stage prefetch ----
    s16x8 wA[KC16], wB[KC16];
    wload(0, wA);
    wload(1, wB);
    int s = 0;
    for (; s + 2 <= NB_F0; s += 2) {
      compute(s, wA);
      wload(s + 2 < NB_F0 ? s + 2 : 0, wA);   // reissue post-use (reg WAR ok)
      compute(s + 1, wB);
      if (s + 3 < NB_F0) wload(s + 3, wB);
    }
    if (s < NB_F0) compute(s, wA);   // odd tail (S=39)

    // ---- epilogue: sums to global; Xn to LDS in A-fragment layout ----
    const float bias_v = bv[wv * 32 + col];
#pragma unroll
    for (int P = 0; P < 2; ++P) {
#pragma unroll
      for (int bh = 0; bh < 2; ++bh) {
        const int bl = 2 * P + bh;
        float v[8];
#pragma unroll
        for (int m = 0; m < 8; ++m) v[m] = Xacc[P][bh * 8 + m] + bias_v;
        if (xn) {
#pragma unroll
          for (int m = 0; m < 8; ++m) {
            const int d = (m & 3) + 8 * ((m >> 2) & 1) + 4 * L;
            xn[(bl * 16 + d) * 128 + wv * 32 + col] = rne_bf16(v[m]);
          }
        }
        float tot = ((v[0] + v[1]) + (v[2] + v[3])) +
                    ((v[4] + v[5]) + (v[6] + v[7]));
        tot += __shfl_xor(tot, 32);
        if (lane < 32) op[(size_t)(bblk + bl) * 384 + wv * 32 + lane] = tot;
      }
    }
  };

  layer(IC<4>{}, Wf0, X0T + (size_t)bblk * (16 * 64), bias0, outp + 0,   Xa);
  __syncthreads();   // publish X1 before L1 af reads
  layer(IC<8>{}, Wf1, Xa,                             bias1, outp + 128, Xb);
  __syncthreads();   // publish X2 before L2 af reads
  layer(IC<8>{}, Wf2, Xb,                             bias2, outp + 256,
        (unsigned short*)nullptr);
}

extern "C" void kernel_launch(void* const* d_in, const int* in_sizes, int n_in,
                              void* d_out, int out_size, void* d_ws, size_t ws_size,
                              hipStream_t stream) {
  (void)in_sizes; (void)n_in; (void)out_size; (void)ws_size;
  const float* X0g = (const float*)d_in[0];
  const float* W0  = (const float*)d_in[1];
  const float* b0  = (const float*)d_in[2];
  const float* W1  = (const float*)d_in[3];
  const float* b1  = (const float*)d_in[4];
  const float* W2  = (const float*)d_in[5];
  const float* b2  = (const float*)d_in[6];
  float* out = (float*)d_out;

  char* p = (char*)d_ws;
  unsigned short* X0T = (unsigned short*)p; p += (size_t)NB_B * 16 * 64 * 2;
  unsigned short* X0c = (unsigned short*)p; p += (size_t)NB_B * NB_F0 * 16 * 2;
  unsigned short* Wf0 = (unsigned short*)p; p += (size_t)NB_F0 * 4 * 4 * 512 * 2;
  unsigned short* Wf1 = (unsigned short*)p; p += (size_t)NB_F0 * 4 * 8 * 512 * 2;
  unsigned short* Wf2 = (unsigned short*)p; p += (size_t)NB_F0 * 4 * 8 * 512 * 2;

  hipLaunchKernelGGL(prep_x0_kernel, dim3(NB_B), dim3(256), 0, stream,
                     X0g, X0T, X0c);
  const int tw0  = NB_F0 * 4 * 4 * 512;   // KC16=4
  const int tw12 = NB_F0 * 4 * 8 * 512;   // KC16=8
  hipLaunchKernelGGL(prep_w_kernel, dim3((tw0 + 255) / 256), dim3(256), 0, stream,
                     W0, Wf0, 39, 2, tw0);
  hipLaunchKernelGGL(prep_w_kernel, dim3((tw12 + 255) / 256), dim3(256), 0, stream,
                     W1, Wf1, 128, 3, tw12);
  hipLaunchKernelGGL(prep_w_kernel, dim3((tw12 + 255) / 256), dim3(256), 0, stream,
                     W2, Wf2, 128, 3, tw12);

  hipLaunchKernelGGL(cin_fused, dim3(NB_B / 4), dim3(256), 0, stream,
                     Wf0, Wf1, Wf2, X0T, X0c, b0, b1, b2, out);
}

// Round 8
// 305.346 us; speedup vs baseline: 1.2130x; 1.0091x over previous
//
#include <hip/hip_runtime.h>
#include <stdint.h>

// CIN layers: Xn[b,h,d] = sum_{j,k} W[h,j,k] * X0[b,j,d] * Xi[b,k,d] + bias[h]
// y[d,h] = sum_k Xi*W (mfma_32x32x16, A rows m=b'*16+d, B cols=32h), then
// Xacc += x0[b,j,d]*y.
// R17 post-mortem: fusion landed (WRITE 38->6MB, one 262us dispatch == sum of
// unfused layers) but exposed two NEW consumers: (1) SQ_LDS_BANK_CONFLICT
// 7.86M -- the L1/L2 af reads from Xa/Xb at row stride 128 shorts (256B) are
// a 32-way conflict (G4), ~13us on the post-barrier critical path; (2)
// VALUBusy 34.8% with 16/24 VALU ops per (s,P) being bf16->f32 unpack of x0.
// R18: (a) pad Xa/Xb rows to 130 shorts: lane stride 65 words -> bank
// (65i)%32 = i, all 32 lanes distinct, <=2-way everywhere (free, m136);
// (b) stage x0 factors as f32 (X0f prep, d-permuted): x0-scale = 4 broadcast
// ds_read_b128 + 8 v_pk_fma_f32, ZERO unpack VALU (also kills x0 double-
// rounding). LDS 43.3KB. Inner loop / fusion structure unchanged (R16/R17:
// j-major, W global->reg ping-pong, zero in-loop barriers).

#define NB_F0 39
#define NB_H  128
#define NB_B  4096
#define XROW 130   // padded k-row stride (shorts) for Xa/Xb

typedef float f32x4  __attribute__((ext_vector_type(4)));
typedef float f32x16 __attribute__((ext_vector_type(16)));
typedef short s16x8  __attribute__((ext_vector_type(8)));

template <int N> struct IC { static constexpr int value = N; };

__device__ __forceinline__ unsigned short rne_bf16(float f) {
  union { float f; unsigned u; } v; v.f = f;
  return (unsigned short)((v.u + 0x7fffu + ((v.u >> 16) & 1u)) >> 16);
}

// X0 f32 [B][39][16] -> X0T bf16 [B][16][64] (k=j zero-padded, layer-0 A source)
//                    -> X0f f32  [B][39][16] with d-PERMUTED inner dim
//   (pos<->d swap bits 2,3) so a lane's 8 x0 factors for MFMA regs r=0..7
//   (d = (r&3)+8*((r>>2)&1)+4L) are one contiguous 32B run.
__global__ void prep_x0_kernel(const float* __restrict__ X0g,
                               unsigned short* __restrict__ X0T,
                               float* __restrict__ X0f) {
  const int b = blockIdx.x;
  const int t = threadIdx.x;
  {
    const int d  = t >> 4;
    const int k4 = (t & 15) << 2;
    unsigned short vv[4];
#pragma unroll
    for (int i = 0; i < 4; ++i) {
      const int k = k4 + i;
      vv[i] = (k < NB_F0) ? rne_bf16(X0g[(size_t)b * (NB_F0 * 16) + k * 16 + d])
                          : (unsigned short)0;
    }
    ushort4 pk; pk.x = vv[0]; pk.y = vv[1]; pk.z = vv[2]; pk.w = vv[3];
    *(ushort4*)&X0T[((size_t)b * 16 + d) * 64 + k4] = pk;
  }
  for (int idx = t; idx < NB_F0 * 16; idx += 256) {
    const int j = idx >> 4, pos = idx & 15;
    const int d = (pos & 3) | (((pos >> 3) & 1) << 2) | (((pos >> 2) & 1) << 3);
    X0f[(size_t)b * (NB_F0 * 16) + idx] =
        X0g[(size_t)b * (NB_F0 * 16) + j * 16 + d];
  }
}

// W f32 [128][39*Fi] -> Wf bf16 fragment-linear for 32x32x16 B-operand:
//   Wf[(((j*4 + t)*KC16 + c)*64 + lane)*8 + i]
//     = W[h = t*32 + (lane&31)][j, k = c*16 + (lane>>5)*8 + i]   (0 if k>=Fi)
__global__ void prep_w_kernel(const float* __restrict__ Wsrc,
                              unsigned short* __restrict__ Wdst,
                              int Fi, int kshift, int total) {
  int idx = blockIdx.x * 256 + threadIdx.x;
  if (idx >= total) return;
  const int i    = idx & 7;
  const int lane = (idx >> 3) & 63;
  const int c    = (idx >> 9) & ((1 << kshift) - 1);
  const int jt   = idx >> (9 + kshift);
  const int t    = jt & 3;
  const int j    = jt >> 2;
  const int h = t * 32 + (lane & 31);
  const int k = c * 16 + ((lane >> 5) << 3) + i;
  unsigned short v = 0;
  if (k < Fi) v = rne_bf16(Wsrc[(size_t)h * (NB_F0 * Fi) + j * Fi + k]);
  Wdst[idx] = v;
}

__global__ __launch_bounds__(256, 1) void cin_fused(
    const unsigned short* __restrict__ Wf0,
    const unsigned short* __restrict__ Wf1,
    const unsigned short* __restrict__ Wf2,
    const unsigned short* __restrict__ X0T,  // [B][16][64] bf16 (k zero-pad)
    const float* __restrict__ X0f,           // [B][39][16] f32, d-permuted
    const float* __restrict__ bias0,
    const float* __restrict__ bias1,
    const float* __restrict__ bias2,
    float* __restrict__ outp)                // [B][384]
{
  __shared__ __attribute__((aligned(16))) float x0f[4 * NB_F0 * 16];
  __shared__ __attribute__((aligned(16))) unsigned short Xa[4 * 16 * XROW];
  __shared__ __attribute__((aligned(16))) unsigned short Xb[4 * 16 * XROW];

  const int tid  = threadIdx.x;
  const int lane = tid & 63;
  const int wv   = tid >> 6;        // h-tile: h = wv*32 + col
  const int L    = lane >> 5;       // k-half selector within a 16-chunk
  const int col  = lane & 31;       // A row m / B col
  const int bblk = blockIdx.x * 4;  // 4 b per block

  // ---- stage x0 factors (f32 d-permuted, flat coalesced copy) ----
  {
    const float* src = X0f + (size_t)bblk * (NB_F0 * 16);
    for (int c = tid; c < (4 * NB_F0 * 16) / 4; c += 256)
      *(f32x4*)&x0f[c * 4] = *(const f32x4*)&src[c * 4];
  }
  __syncthreads();   // publish x0f

  const int x0base = L * 8;   // all waves share the block's 4 b (broadcast)

  // One CIN layer. KC16 = K-chunks (4 for Fi=64-pad, 8 for Fi=128);
  // AST = Xi A-fragment row stride in shorts (64 global X0T, XROW LDS).
  auto layer = [&](auto kc, auto ast, const unsigned short* __restrict__ Wl,
                   const unsigned short* af_base, const float* __restrict__ bv,
                   float* __restrict__ op, unsigned short* xn) {
    constexpr int KC16 = decltype(kc)::value;
    constexpr int AST  = decltype(ast)::value;

    // ---- Xi A-fragments: chain P covers b_local = 2P + (col>>4) ----
    s16x8 af[2][KC16];
#pragma unroll
    for (int P = 0; P < 2; ++P) {
      const unsigned short* base = af_base +
          (size_t)(2 * P + (col >> 4)) * (16 * AST) + (col & 15) * AST + L * 8;
#pragma unroll
      for (int c = 0; c < KC16; ++c) af[P][c] = *(const s16x8*)(base + c * 16);
    }

    f32x16 Xacc[2], kZero;
#pragma unroll
    for (int r = 0; r < 16; ++r) kZero[r] = 0.f;
#pragma unroll
    for (int P = 0; P < 2; ++P) Xacc[P] = kZero;

    // ---- W fragments straight from global (L2-hot) into registers ----
    const s16x8* __restrict__ W8 = (const s16x8*)Wl;
    auto wload = [&](int j, s16x8 (&w)[KC16]) {
      const s16x8* p = W8 + ((size_t)(j * 4 + wv) * KC16) * 64 + lane;
#pragma unroll
      for (int c = 0; c < KC16; ++c) w[c] = p[c * 64];
    };

    auto compute = [&](int s, const s16x8 (&w)[KC16]) {
#pragma unroll
      for (int P = 0; P < 2; ++P) {
        f32x16 y = __builtin_amdgcn_mfma_f32_32x32x16_bf16(af[P][0], w[0],
                                                           kZero, 0, 0, 0);
#pragma unroll
        for (int c = 1; c < KC16; ++c)
          y = __builtin_amdgcn_mfma_f32_32x32x16_bf16(af[P][c], w[c], y,
                                                      0, 0, 0);
        // x0 scale: regs 0-7 <- b'=2P (this lane's L 8-run), 8-15 <- 2P+1.
        // f32 factors: broadcast ds_read_b128 x4, zero unpack VALU.
        const float* xr0 = &x0f[x0base + (2 * P + 0) * (NB_F0 * 16) + s * 16];
        const float* xr1 = &x0f[x0base + (2 * P + 1) * (NB_F0 * 16) + s * 16];
        const f32x4 a0 = *(const f32x4*)(xr0);
        const f32x4 a1 = *(const f32x4*)(xr0 + 4);
        const f32x4 a2 = *(const f32x4*)(xr1);
        const f32x4 a3 = *(const f32x4*)(xr1 + 4);
        f32x16 xsc;
#pragma unroll
        for (int i = 0; i < 4; ++i) {
          xsc[i]      = a0[i];
          xsc[4 + i]  = a1[i];
          xsc[8 + i]  = a2[i];
          xsc[12 + i] = a3[i];
        }
        Xacc[P] = __builtin_elementwise_fma(xsc, y, Xacc[P]);
      }
    };

    // ---- barrier-free main loop: W reg ping-pong, 1-stage prefetch ----
    s16x8 wA[KC16], wB[KC16];
    wload(0, wA);
    wload(1, wB);
    int s = 0;
    for (; s + 2 <= NB_F0; s += 2) {
      compute(s, wA);
      wload(s + 2 < NB_F0 ? s + 2 : 0, wA);   // reissue post-use (reg WAR ok)
      compute(s + 1, wB);
      if (s + 3 < NB_F0) wload(s + 3, wB);
    }
    if (s < NB_F0) compute(s, wA);   // odd tail (S=39)

    // ---- epilogue: sums to global; Xn to LDS in A-fragment layout ----
    const float bias_v = bv[wv * 32 + col];
#pragma unroll
    for (int P = 0; P < 2; ++P) {
#pragma unroll
      for (int bh = 0; bh < 2; ++bh) {
        const int bl = 2 * P + bh;
        float v[8];
#pragma unroll
        for (int m = 0; m < 8; ++m) v[m] = Xacc[P][bh * 8 + m] + bias_v;
        if (xn) {
#pragma unroll
          for (int m = 0; m < 8; ++m) {
            const int d = (m & 3) + 8 * ((m >> 2) & 1) + 4 * L;
            xn[(bl * 16 + d) * XROW + wv * 32 + col] = rne_bf16(v[m]);
          }
        }
        float tot = ((v[0] + v[1]) + (v[2] + v[3])) +
                    ((v[4] + v[5]) + (v[6] + v[7]));
        tot += __shfl_xor(tot, 32);
        if (lane < 32) op[(size_t)(bblk + bl) * 384 + wv * 32 + lane] = tot;
      }
    }
  };

  layer(IC<4>{}, IC<64>{}, Wf0, X0T + (size_t)bblk * (16 * 64),
        bias0, outp + 0, Xa);
  __syncthreads();   // publish X1 before L1 af reads
  layer(IC<8>{}, IC<XROW>{}, Wf1, Xa, bias1, outp + 128, Xb);
  __syncthreads();   // publish X2 before L2 af reads
  layer(IC<8>{}, IC<XROW>{}, Wf2, Xb, bias2, outp + 256,
        (unsigned short*)nullptr);
}

extern "C" void kernel_launch(void* const* d_in, const int* in_sizes, int n_in,
                              void* d_out, int out_size, void* d_ws, size_t ws_size,
                              hipStream_t stream) {
  (void)in_sizes; (void)n_in; (void)out_size; (void)ws_size;
  const float* X0g = (const float*)d_in[0];
  const float* W0  = (const float*)d_in[1];
  const float* b0  = (const float*)d_in[2];
  const float* W1  = (const float*)d_in[3];
  const float* b1  = (const float*)d_in[4];
  const float* W2  = (const float*)d_in[5];
  const float* b2  = (const float*)d_in[6];
  float* out = (float*)d_out;

  char* p = (char*)d_ws;
  unsigned short* X0T = (unsigned short*)p; p += (size_t)NB_B * 16 * 64 * 2;
  float*          X0f = (float*)p;          p += (size_t)NB_B * NB_F0 * 16 * 4;
  unsigned short* Wf0 = (unsigned short*)p; p += (size_t)NB_F0 * 4 * 4 * 512 * 2;
  unsigned short* Wf1 = (unsigned short*)p; p += (size_t)NB_F0 * 4 * 8 * 512 * 2;
  unsigned short* Wf2 = (unsigned short*)p; p += (size_t)NB_F0 * 4 * 8 * 512 * 2;

  hipLaunchKernelGGL(prep_x0_kernel, dim3(NB_B), dim3(256), 0, stream,
                     X0g, X0T, X0f);
  const int tw0  = NB_F0 * 4 * 4 * 512;   // KC16=4
  const int tw12 = NB_F0 * 4 * 8 * 512;   // KC16=8
  hipLaunchKernelGGL(prep_w_kernel, dim3((tw0 + 255) / 256), dim3(256), 0, stream,
                     W0, Wf0, 39, 2, tw0);
  hipLaunchKernelGGL(prep_w_kernel, dim3((tw12 + 255) / 256), dim3(256), 0, stream,
                     W1, Wf1, 128, 3, tw12);
  hipLaunchKernelGGL(prep_w_kernel, dim3((tw12 + 255) / 256), dim3(256), 0, stream,
                     W2, Wf2, 128, 3, tw12);

  hipLaunchKernelGGL(cin_fused, dim3(NB_B / 4), dim3(256), 0, stream,
                     Wf0, Wf1, Wf2, X0T, X0f, b0, b1, b2, out);
}